// Round 4
// baseline (146.898 us; speedup 1.0000x reference)
//
#include <hip/hip_runtime.h>
#include <math.h>

#define HH 256
#define WW 256
#define BB 8
#define MM 256
#define NN (HH * WW)
#define PP 2                              // pixels per thread (same row)
#define TPB 256
#define PIX_PER_BLK (TPB * PP)            // 512 = 2 rows
#define BLKS_PER_B (NN / PIX_PER_BLK)     // 128
#define NBLK (BB * BLKS_PER_B)            // 1024 blocks = 4 per CU

#define EPSI 1e-6f
#define MAXD 362.03867196751236f
#define EPS_OVER_MAXD (1e-6f / 362.03867196751236f)

static __device__ __forceinline__ float asqrt(float x) {
    return __builtin_amdgcn_sqrtf(x);     // single v_sqrt_f32
}

// ws layout (uints): [0] counter | [16..16+2047] gmin (INVERTED float bits:
// memset-0 == +inf under unsigned atomicMax) | [2064..] per-block partials.
__global__ __launch_bounds__(256, 4) void whd_fused(
    const float* __restrict__ pm, const float* __restrict__ gt,
    const float* __restrict__ osz, float* __restrict__ out,
    unsigned* __restrict__ ws0)
{
    unsigned* ctr  = ws0;
    unsigned* gmin = ws0 + 16;                 // BB*MM
    unsigned* part = ws0 + 16 + BB * MM;       // NBLK*2

    __shared__ __align__(16) float2 sgt[MM];   // scaled GT (pairs read as float4)
    __shared__ int    smin2[MM];  // de-interleaved: [0..127] m=2j, [128..255] m=2j+1
    __shared__ float  swred[8];
    __shared__ float  tsum[BB];
    __shared__ float  gred[4];
    __shared__ int    lastFlag;

    const int tid = threadIdx.x;
    const int blk = blockIdx.x;   // 0..127
    const int b   = blockIdx.y;

    const float nfY = osz[b * 2 + 0] * (1.0f / HH);
    const float nfX = osz[b * 2 + 1] * (1.0f / WW);

    // stage scaled GT + init column minima
    {
        const float2 g = ((const float2*)gt)[b * MM + tid];
        sgt[tid]   = make_float2(g.x * nfY, g.y * nfX);
        smin2[tid] = 0x7F800000;   // +inf
    }

    // this thread's 2 pixels: one row, 2 consecutive cols (coalesced float2)
    const int   row  = blk * 2 + (tid >> 7);
    const int   col0 = (tid & 127) * 2;
    const float y    = (float)row * nfY;

    const float2 pv = *(const float2*)(pm + b * NN + row * WW + col0);
    const float p0 = pv.x, p1 = pv.y;
    const float x0 = (float)col0 * nfX;
    const float x1 = (float)(col0 + 1) * nfX;
    const float q0 = p0 * p0, q1 = p1 * p1;
    const float sc0 = 1.0f / (q0 * q0 + EPS_OVER_MAXD);   // 1/(p^4 + EPS/MAXD)
    const float sc1 = 1.0f / (q1 * q1 + EPS_OVER_MAXD);
    const float c40 = EPSI * sc0, c41 = EPSI * sc1;
    float mind2a = INFINITY, mind2b = INFINITY;

    __syncthreads();

    // ---- main loop: 128 iters x (2 m x 2 px); zero cross-lane ops.
    // ds_read_b128 (2 GT points) rotated per lane -> conflict-free; explicit
    // next-iter prefetch hides LDS latency; 2 ds_min to 4B-stride addrs (free).
    const float4* sgt4 = (const float4*)sgt;
    int idx = tid & 127;
    float4 g = sgt4[idx];
    #pragma unroll 4
    for (int mm = 0; mm < 128; ++mm) {
        const int   nidx = (idx + 1) & 127;
        const float4 gn  = sgt4[nidx];          // prefetch next pair
        float ey0 = y - g.x;  ey0 *= ey0;       // m0 = 2*idx
        float ey1 = y - g.z;  ey1 *= ey1;       // m1 = 2*idx+1
        const float dx00 = x0 - g.y;
        const float dx10 = x1 - g.y;
        const float dx01 = x0 - g.w;
        const float dx11 = x1 - g.w;
        const float d00 = fmaf(dx00, dx00, ey0);
        const float d10 = fmaf(dx10, dx10, ey0);
        const float d01 = fmaf(dx01, dx01, ey1);
        const float d11 = fmaf(dx11, dx11, ey1);
        mind2a = fminf(mind2a, fminf(d00, d01));
        mind2b = fminf(mind2b, fminf(d10, d11));
        const float v00 = fmaf(asqrt(d00), sc0, c40);
        const float v10 = fmaf(asqrt(d10), sc1, c41);
        const float v01 = fmaf(asqrt(d01), sc0, c40);
        const float v11 = fmaf(asqrt(d11), sc1, c41);
        atomicMin(&smin2[idx],       __float_as_int(fminf(v00, v10)));
        atomicMin(&smin2[128 + idx], __float_as_int(fminf(v01, v11)));
        idx = nidx;
        g   = gn;
    }

    // ---- term1 partials (thread-exclusive pixels -> one wave reduce)
    float sum0 = p0 + p1;
    float sum1 = fmaf(p0, asqrt(mind2a), p1 * asqrt(mind2b));
    #pragma unroll
    for (int off = 32; off; off >>= 1) {
        sum0 += __shfl_down(sum0, off, 64);
        sum1 += __shfl_down(sum1, off, 64);
    }
    if ((tid & 63) == 0) { swred[(tid >> 6) * 2] = sum0; swred[(tid >> 6) * 2 + 1] = sum1; }
    __syncthreads();   // also orders all smin2 atomics

    const int blin = b * BLKS_PER_B + blk;
    if (tid == 0) {
        const float s0 = (swred[0] + swred[2]) + (swred[4] + swred[6]);
        const float s1 = (swred[1] + swred[3]) + (swred[5] + swred[7]);
        atomicExch(&part[blin * 2 + 0], __float_as_uint(s0));
        atomicExch(&part[blin * 2 + 1], __float_as_uint(s1));
    }
    // merge block's per-m minima into global (inverted bits, unsigned max)
    {
        const int m = ((tid & 127) << 1) | (tid >> 7);   // de-interleave map
        atomicMax(&gmin[b * MM + m], ~(unsigned)smin2[tid]);
    }

    // ---- last-block combine
    __threadfence();
    if (tid == 0) lastFlag = (atomicAdd(ctr, 1u) == NBLK - 1);
    __syncthreads();
    if (!lastFlag) return;
    __threadfence();

    // term2: mean of clipped per-(b,m) minima
    float gacc = 0.0f;
    #pragma unroll
    for (int q = 0; q < BB; ++q) {
        const float v = __uint_as_float(~atomicOr(&gmin[q * MM + tid], 0u));
        gacc += fminf(fmaxf(v, 0.0f), MAXD);
    }
    #pragma unroll
    for (int off = 32; off; off >>= 1) gacc += __shfl_down(gacc, off, 64);
    if ((tid & 63) == 0) gred[tid >> 6] = gacc;

    // term1: per-batch ratios from per-block partials (8 batches x 32 lanes)
    {
        const int bb = tid >> 5, r = tid & 31;
        float s0 = 0.0f, s1 = 0.0f;
        #pragma unroll
        for (int q = 0; q < BLKS_PER_B / 32; ++q) {   // 4
            const int bl = bb * BLKS_PER_B + r + q * 32;
            s0 += __uint_as_float(atomicOr(&part[bl * 2 + 0], 0u));
            s1 += __uint_as_float(atomicOr(&part[bl * 2 + 1], 0u));
        }
        #pragma unroll
        for (int off = 16; off; off >>= 1) {
            s0 += __shfl_down(s0, off, 32);
            s1 += __shfl_down(s1, off, 32);
        }
        if (r == 0) tsum[bb] = s1 / (s0 + EPSI);
    }
    __syncthreads();
    if (tid == 0) {
        float t1 = 0.0f;
        #pragma unroll
        for (int q = 0; q < BB; ++q) t1 += tsum[q];
        const float g2 = (gred[0] + gred[1]) + (gred[2] + gred[3]);
        out[0] = t1 * (1.0f / BB) + g2 * (1.0f / (BB * MM));
    }
}

extern "C" void kernel_launch(void* const* d_in, const int* in_sizes, int n_in,
                              void* d_out, int out_size, void* d_ws, size_t ws_size,
                              hipStream_t stream) {
    const float* pm  = (const float*)d_in[0];   // [B, H, W]
    const float* gt  = (const float*)d_in[1];   // [B, M, 2]
    const float* osz = (const float*)d_in[2];   // [B, 2]
    float* out = (float*)d_out;
    unsigned* ws0 = (unsigned*)d_ws;

    // counter + gmin zero-init (gmin inverted bits: 0 == +inf)
    hipMemsetAsync(ws0, 0, (16 + BB * MM) * sizeof(unsigned), stream);

    dim3 grid(BLKS_PER_B, BB);
    whd_fused<<<grid, 256, 0, stream>>>(pm, gt, osz, out, ws0);
}